// Round 9
// baseline (173.062 us; speedup 1.0000x reference)
//
#include <hip/hip_runtime.h>
#include <hip/hip_bf16.h>
#include <math.h>

#define SEQ 512
#define DM 512
#define NH 8
#define DKH 64
#define EPSV 1e-6f
#define LN2F 0.6931471805599453f

typedef __attribute__((ext_vector_type(8))) short short8v;
typedef __attribute__((ext_vector_type(8))) unsigned short ushort8v;
typedef __attribute__((ext_vector_type(16))) float f32x16;

__device__ inline unsigned short f2bf(float x) {
  union { float f; unsigned u; } v; v.f = x;
  unsigned r = v.u + 0x7FFFu + ((v.u >> 16) & 1u);
  return (unsigned short)(r >> 16);
}
__device__ inline float bf2f(unsigned short h) {
  union { float f; unsigned u; } v; v.u = ((unsigned)h) << 16;
  return v.f;
}

// ---------------------------------------------------------------------------
// Kernel C: convert 12 fp32 512x512 matrices (6 X, 6 W) into a 3-level bf16
// split (x = h1 + h2 + h3, representation error ~2^-27 |x|) in fragment-ready
// layout: pack[m][level][panel p][k-octet ko][row r][8 bf16].
// ---------------------------------------------------------------------------
struct ConvArgs { const float* src[12]; };

__global__ __launch_bounds__(256) void convert_kernel(ConvArgs a,
                                                      unsigned short* __restrict__ pack) {
  const int m = blockIdx.x >> 7;                        // matrix 0..11
  const int g = ((blockIdx.x & 127) << 8) + threadIdx.x; // 0..32767
  const int r = g & 31, ko = (g >> 5) & 63, p = g >> 11;
  const float* src = a.src[m] + (p * 32 + r) * DM + ko * 8;
  float4 x0 = *(const float4*)src;
  float4 x1 = *(const float4*)(src + 4);
  float xs[8] = {x0.x, x0.y, x0.z, x0.w, x1.x, x1.y, x1.z, x1.w};
  ushort8v h1, h2, h3;
#pragma unroll
  for (int e = 0; e < 8; ++e) {
    unsigned short a1 = f2bf(xs[e]);
    float r1 = xs[e] - bf2f(a1);
    unsigned short a2 = f2bf(r1);
    float r2 = r1 - bf2f(a2);
    h1[e] = a1; h2[e] = a2; h3[e] = f2bf(r2);
  }
  unsigned short* dh = pack + (size_t)m * 786432 + p * 16384 + ko * 256 + r * 8;
  *(ushort8v*)dh = h1;
  *(ushort8v*)(dh + 262144) = h2;
  *(ushort8v*)(dh + 524288) = h3;
}

// ---------------------------------------------------------------------------
// Kernel P: six 512^3 GEMMs C = X*W^T + b via 3-level bf16 split MFMA.
// Epilogue fuses the prep squaring: p=3,4 -> v^2+eps ; p=5 -> v^2.
// 1D grid 384 with bijective XCD swizzle (384 = 8 x 48): each XCD works a
// contiguous 48-block span (6 A-panel rows x 8 bx) -> A-panel L2 reuse.
// C/D layout (verified m74/m101): col = lane&31, row = (i&3)+8*(i>>2)+4*(lane>>5).
// ---------------------------------------------------------------------------
struct GemmArgs { const float* bias[6]; float* out[6]; };

__global__ __launch_bounds__(512) void mfma_proj_kernel(const unsigned short* __restrict__ pack,
                                                        GemmArgs ga) {
  const int bid = blockIdx.x;                 // 0..383
  const int swz = (bid & 7) * 48 + (bid >> 3);
  const int p = swz >> 6;
  const int rem = swz & 63;
  const int by = rem >> 3, bx = rem & 7;
  const int t = threadIdx.x, l = t & 63, w = t >> 6;
  const int qd = w & 3, kh = w >> 2;
  const int rowblk = qd >> 1, colblk = qd & 1;
  const int r = l & 31, koff = l >> 5;

  const unsigned short* A = pack + (size_t)p * 786432;
  const unsigned short* B = pack + (size_t)(6 + p) * 786432;
  const int pa = by * 2 + rowblk, pb = bx * 2 + colblk;
  const int ko0 = kh * 32 + koff;
  const size_t aoff = (size_t)pa * 16384 + (size_t)ko0 * 256 + r * 8;
  const size_t boff = (size_t)pb * 16384 + (size_t)ko0 * 256 + r * 8;
  const short8v* A1 = (const short8v*)(A + aoff);
  const short8v* A2 = (const short8v*)(A + 262144 + aoff);
  const short8v* A3 = (const short8v*)(A + 524288 + aoff);
  const short8v* B1 = (const short8v*)(B + boff);
  const short8v* B2 = (const short8v*)(B + 262144 + boff);
  const short8v* B3 = (const short8v*)(B + 524288 + boff);

  f32x16 acc = {};
#pragma unroll 2
  for (int s = 0; s < 16; ++s) {
    short8v a1 = A1[(size_t)s * 64];
    short8v a2 = A2[(size_t)s * 64];
    short8v a3 = A3[(size_t)s * 64];
    short8v b1 = B1[(size_t)s * 64];
    short8v b2 = B2[(size_t)s * 64];
    short8v b3 = B3[(size_t)s * 64];
    acc = __builtin_amdgcn_mfma_f32_32x32x16_bf16(a1, b1, acc, 0, 0, 0);
    acc = __builtin_amdgcn_mfma_f32_32x32x16_bf16(a2, b1, acc, 0, 0, 0);
    acc = __builtin_amdgcn_mfma_f32_32x32x16_bf16(a1, b2, acc, 0, 0, 0);
    acc = __builtin_amdgcn_mfma_f32_32x32x16_bf16(a3, b1, acc, 0, 0, 0);
    acc = __builtin_amdgcn_mfma_f32_32x32x16_bf16(a2, b2, acc, 0, 0, 0);
    acc = __builtin_amdgcn_mfma_f32_32x32x16_bf16(a1, b3, acc, 0, 0, 0);
  }

  __shared__ float red[4][32][33];
  if (kh == 1) {
#pragma unroll
    for (int i = 0; i < 16; ++i) {
      int row = (i & 3) + 8 * (i >> 2) + 4 * (l >> 5);
      red[qd][row][r] = acc[i];
    }
  }
  __syncthreads();
  if (kh == 0) {
    const int colg = bx * 64 + colblk * 32 + r;
    const float bias = ga.bias[p][colg];
    float* C = ga.out[p];
    const int rowbase = by * 64 + rowblk * 32;
#pragma unroll
    for (int i = 0; i < 16; ++i) {
      int row = (i & 3) + 8 * (i >> 2) + 4 * (l >> 5);
      float v = acc[i] + red[qd][row][r] + bias;
      if (p >= 3) v = fmaf(v, v, (p == 5) ? 0.f : EPSV);   // fused prep
      C[(size_t)(rowbase + row) * DM + colg] = v;
    }
  }
}

// ---------------------------------------------------------------------------
// Kernel D: distance matrix, causal 64x32 tiles. h = blk%8: with round-robin
// block->XCD dispatch each XCD works one head (512KB working set, fits its
// private 4MB L2). 576 blocks, thread = 4q x 2k microtile, inline log2 sums.
// ---------------------------------------------------------------------------
__global__ __launch_bounds__(256) void dist_kernel(const float* __restrict__ aq,
                                                   const float* __restrict__ ak,
                                                   const float* __restrict__ mq,
                                                   const float* __restrict__ mk,
                                                   float* __restrict__ dist) {
  const int blk = blockIdx.x;
  const int h = blk & 7;            // XCD-locality: one head per XCD
  const int tt = blk >> 3;          // 0..71
  int qt = (int)sqrtf((float)tt);
  while ((qt + 1) * (qt + 2) <= tt) ++qt;
  while (qt * (qt + 1) > tt) --qt;
  const int kt = tt - qt * (qt + 1);   // 0 .. 2*qt+1

  __shared__ float aqs[64][68], mqs[64][68], aks[32][68], mks[32][68];
  __shared__ float lsum[96][2];
  const int t = threadIdx.x;
#pragma unroll
  for (int i = 0; i < 4; ++i) {
    int idx = t + 256 * i;          // 0..1023: q rows
    int r = idx >> 4, c4 = idx & 15;
    int gq = (qt * 64 + r) * DM + h * 64 + c4 * 4;
    *(float4*)&aqs[r][c4 * 4] = *(const float4*)&aq[gq];
    *(float4*)&mqs[r][c4 * 4] = *(const float4*)&mq[gq];
  }
#pragma unroll
  for (int i = 0; i < 2; ++i) {
    int idx = t + 256 * i;          // 0..511: k rows
    int r = idx >> 4, c4 = idx & 15;
    int gk = (kt * 32 + r) * DM + h * 64 + c4 * 4;
    *(float4*)&aks[r][c4 * 4] = *(const float4*)&ak[gk];
    *(float4*)&mks[r][c4 * 4] = *(const float4*)&mk[gk];
  }
  __syncthreads();

  if (t < 192) {
    int row = t >> 1, par = t & 1;
    const float* src = (row < 64) ? &aqs[row][0] : &aks[row - 64][0];
    float s = 0.f;
#pragma unroll
    for (int d = 0; d < 32; ++d) s += __log2f(src[par * 32 + d]);
    lsum[row][par] = s;
  }
  __syncthreads();

  const int tq = t >> 4, tk = t & 15;
  float accl[4][2], acct[4][2];
#pragma unroll
  for (int i = 0; i < 4; ++i)
#pragma unroll
    for (int j = 0; j < 2; ++j) { accl[i][j] = 0.f; acct[i][j] = 0.f; }

#pragma unroll 2
  for (int d4 = 0; d4 < 16; ++d4) {
    float4 qa[4], qm[4], ka[2], km[2];
#pragma unroll
    for (int i = 0; i < 4; ++i) {
      qa[i] = *(const float4*)&aqs[tq * 4 + i][d4 * 4];
      qm[i] = *(const float4*)&mqs[tq * 4 + i][d4 * 4];
    }
#pragma unroll
    for (int j = 0; j < 2; ++j) {
      ka[j] = *(const float4*)&aks[tk + 16 * j][d4 * 4];
      km[j] = *(const float4*)&mks[tk + 16 * j][d4 * 4];
    }
#pragma unroll
    for (int i = 0; i < 4; ++i) {
      float qav[4] = {qa[i].x, qa[i].y, qa[i].z, qa[i].w};
      float qmv[4] = {qm[i].x, qm[i].y, qm[i].z, qm[i].w};
#pragma unroll
      for (int j = 0; j < 2; ++j) {
        float kav[4] = {ka[j].x, ka[j].y, ka[j].z, ka[j].w};
        float kmv[4] = {km[j].x, km[j].y, km[j].z, km[j].w};
#pragma unroll
        for (int e = 0; e < 4; ++e) {
          float s = qav[e] + kav[e];
          accl[i][j] += __log2f(s);
          float dm = qmv[e] - kmv[e];
          float rcp = __builtin_amdgcn_rcpf(s - EPSV);
          acct[i][j] = fmaf(dm * dm, rcp, acct[i][j]);
        }
      }
    }
  }

  const int qg0 = qt * 64 + tq * 4;
#pragma unroll
  for (int i = 0; i < 4; ++i) {
    float la2 = lsum[tq * 4 + i][0] + lsum[tq * 4 + i][1];
#pragma unroll
    for (int j = 0; j < 2; ++j) {
      int kg = kt * 32 + tk + 16 * j;
      float lc2 = lsum[64 + tk + 16 * j][0] + lsum[64 + tk + 16 * j][1];
      float dv = (LN2F * (0.5f * accl[i][j] - 0.25f * (la2 + lc2) - 32.f)
                  + 0.25f * acct[i][j]) * 0.125f;
      dist[((size_t)(h * SEQ) + qg0 + i) * SEQ + kg] = dv;
    }
  }
}

// ---------------------------------------------------------------------------
// Kernel S (fused): blocks [0,1024): causal softmax, lane owns k-octet,
// writes attn as bf16 HI-ONLY A-fragment packs (P in [0,1]: bf16 rel err
// 2^-9 adds <= ~0.008 to outputs, within threshold headroom). h = bid%8 for
// XCD head-locality. Blocks [1024,1040): pack Vt hi/lo B-fragments.
// ---------------------------------------------------------------------------
__global__ __launch_bounds__(256) void softmax_pvpack_kernel(const float* __restrict__ dist,
                                                             const float* __restrict__ mv,
                                                             const float* __restrict__ sv2,
                                                             unsigned short* __restrict__ aPack,
                                                             unsigned short* __restrict__ vPack) {
  __shared__ float tile[64][65];
  const int t = threadIdx.x;

  if (blockIdx.x < 1024) {
    const int h = blockIdx.x & 7;            // XCD-locality
    const int qq = blockIdx.x >> 3;          // 0..127
    const int q = qq * 4 + (t >> 6);
    const int l = t & 63;
    const float* row = dist + ((size_t)h * SEQ + q) * SEQ;

    float4 v0 = *(const float4*)&row[l * 8];
    float4 v1 = *(const float4*)&row[l * 8 + 4];
    float vals[8] = {v0.x, v0.y, v0.z, v0.w, v1.x, v1.y, v1.z, v1.w};
    float m = -1e30f;
#pragma unroll
    for (int e = 0; e < 8; ++e) {
      vals[e] = (l * 8 + e <= q) ? vals[e] : -1e30f;
      m = fmaxf(m, vals[e]);
    }
#pragma unroll
    for (int o = 32; o; o >>= 1) m = fmaxf(m, __shfl_xor(m, o, 64));
    float ssum = 0.f;
#pragma unroll
    for (int e = 0; e < 8; ++e) {
      float p = (l * 8 + e <= q) ? __expf(vals[e] - m) : 0.f;
      vals[e] = p;
      ssum += p;
    }
#pragma unroll
    for (int o = 32; o; o >>= 1) ssum += __shfl_xor(ssum, o, 64);
    float rs = 1.f / ssum;

    ushort8v hi;
#pragma unroll
    for (int e = 0; e < 8; ++e) hi[e] = f2bf(vals[e] * rs);
    unsigned short* dst = aPack + (size_t)h * 262144 + (q >> 5) * 16384 + l * 256 + (q & 31) * 8;
    *(ushort8v*)dst = hi;
  } else {
    const int bb = blockIdx.x - 1024;
    const int h = bb >> 1;
    const int mm = bb & 1;
    const float* src = (mm == 0) ? mv : sv2;
    unsigned short* base = vPack + (size_t)(h * 2 + mm) * 65536;

    for (int k0 = 0; k0 < SEQ; k0 += 64) {
      __syncthreads();
#pragma unroll
      for (int i = 0; i < 4; ++i) {
        int idx = t + 256 * i;          // 0..1023
        int r = idx >> 4, c4 = idx & 15;
        float4 v = *(const float4*)&src[(size_t)(k0 + r) * DM + h * 64 + c4 * 4];
        tile[r][c4 * 4 + 0] = v.x; tile[r][c4 * 4 + 1] = v.y;
        tile[r][c4 * 4 + 2] = v.z; tile[r][c4 * 4 + 3] = v.w;
      }
      __syncthreads();
#pragma unroll
      for (int i = 0; i < 2; ++i) {
        int idx = t + 256 * i;          // 0..511
        int d = idx & 63, ko = idx >> 6;
        ushort8v hi, lo;
#pragma unroll
        for (int e = 0; e < 8; ++e) {
          float x = tile[ko * 8 + e][d];
          unsigned short hh = f2bf(x);
          hi[e] = hh;
          lo[e] = f2bf(x - bf2f(hh));
        }
        int koG = (k0 >> 3) + ko;
        unsigned short* dst = base + (d >> 5) * 16384 + koG * 256 + (d & 31) * 8;
        *(ushort8v*)dst = hi;
        *(ushort8v*)(dst + 32768) = lo;
      }
    }
  }
}

// ---------------------------------------------------------------------------
// Kernel V: PV via MFMA, P hi-only: 2 MFMAs per K=16 step (a1b1 + a1b2).
// h = bid%8 for XCD head-locality. Block = (h, 32-row q-tile); 4 waves:
// wave w -> (d-tile = w&1, matrix = w>>1). Causal k-steps only.
// ---------------------------------------------------------------------------
__global__ __launch_bounds__(256) void pv_mfma_kernel(const unsigned short* __restrict__ aPack,
                                                      const unsigned short* __restrict__ vPack,
                                                      float* __restrict__ out) {
  const int h = blockIdx.x & 7;
  const int qt = blockIdx.x >> 3;   // 0..15
  const int t = threadIdx.x, l = t & 63, w = t >> 6;
  const int dt = w & 1, mm = w >> 1;

  const unsigned short* aBase = aPack + (size_t)h * 262144 + qt * 16384
                                + (l >> 5) * 256 + (l & 31) * 8;
  const unsigned short* vBase = vPack + (size_t)(h * 2 + mm) * 65536 + dt * 16384
                                + (l >> 5) * 256 + (l & 31) * 8;

  f32x16 acc = {};
  const int nks = 2 * qt + 2;   // K=16 steps covering k <= qt*32+31
#pragma unroll 2
  for (int s = 0; s < nks; ++s) {
    short8v a1 = *(const short8v*)(aBase + (size_t)s * 512);
    short8v b1 = *(const short8v*)(vBase + (size_t)s * 512);
    short8v b2 = *(const short8v*)(vBase + 32768 + (size_t)s * 512);
    acc = __builtin_amdgcn_mfma_f32_32x32x16_bf16(a1, b1, acc, 0, 0, 0);
    acc = __builtin_amdgcn_mfma_f32_32x32x16_bf16(a1, b2, acc, 0, 0, 0);
  }

  float* dst = out + ((mm == 0) ? 0 : (size_t)NH * SEQ * DKH);
  const int col = dt * 32 + (l & 31);
#pragma unroll
  for (int i = 0; i < 16; ++i) {
    int qrow = (i & 3) + 8 * (i >> 2) + 4 * (l >> 5);
    int q = qt * 32 + qrow;
    float v = acc[i];
    if (mm) v = sqrtf(fmaxf(v, 0.f) + EPSV);
    dst[((size_t)h * SEQ + q) * DKH + col] = v;
  }
}

// ---------------------------------------------------------------------------
extern "C" void kernel_launch(void* const* d_in, const int* in_sizes, int n_in,
                              void* d_out, int out_size, void* d_ws, size_t ws_size,
                              hipStream_t stream) {
  (void)in_sizes; (void)n_in; (void)out_size; (void)ws_size;

  float* ws = (float*)d_ws;
  float* mq = ws;                 // 512*512 each
  float* mk = mq + 262144;
  float* mv = mk + 262144;
  float* sq = mv + 262144;        // aq = sigma_q^2 + eps (proj epilogue)
  float* sk = sq + 262144;        // ak = sigma_k^2 + eps
  float* sv = sk + 262144;        // sv^2
  // pack region: 12 x 3 levels x 512KB = 18 MB, dead after the proj GEMM.
  // Reused as: dist (8 MB) + aPack hi-only (4 MB) + vPack (2 MB).
  unsigned short* pack = (unsigned short*)(sv + 262144);
  float* dist = (float*)pack;                         // [0, 8MB)
  unsigned short* aPack = pack + 4194304;             // [8MB, 12MB)
  unsigned short* vPack = pack + 6291456;             // [12MB, 14MB)

  ConvArgs ca;
  ca.src[0] = (const float*)d_in[0];
  ca.src[1] = (const float*)d_in[1];
  ca.src[2] = (const float*)d_in[2];
  ca.src[3] = (const float*)d_in[3];
  ca.src[4] = (const float*)d_in[4];
  ca.src[5] = (const float*)d_in[5];
  ca.src[6] = (const float*)d_in[6];
  ca.src[7] = (const float*)d_in[8];
  ca.src[8] = (const float*)d_in[10];
  ca.src[9] = (const float*)d_in[12];
  ca.src[10] = (const float*)d_in[14];
  ca.src[11] = (const float*)d_in[16];

  GemmArgs gaArgs;
  gaArgs.bias[0] = (const float*)d_in[7];  gaArgs.out[0] = mq;
  gaArgs.bias[1] = (const float*)d_in[9];  gaArgs.out[1] = mk;
  gaArgs.bias[2] = (const float*)d_in[11]; gaArgs.out[2] = mv;
  gaArgs.bias[3] = (const float*)d_in[13]; gaArgs.out[3] = sq;
  gaArgs.bias[4] = (const float*)d_in[15]; gaArgs.out[4] = sk;
  gaArgs.bias[5] = (const float*)d_in[17]; gaArgs.out[5] = sv;

  convert_kernel<<<12 * 128, 256, 0, stream>>>(ca, pack);

  mfma_proj_kernel<<<384, 512, 0, stream>>>(pack, gaArgs);

  dist_kernel<<<8 * 72, 256, 0, stream>>>(sq, sk, mq, mk, dist);

  softmax_pvpack_kernel<<<1040, 256, 0, stream>>>(dist, mv, sv, aPack, vPack);

  pv_mfma_kernel<<<128, 256, 0, stream>>>(aPack, vPack, (float*)d_out);
}

// Round 10
// 159.787 us; speedup vs baseline: 1.0831x; 1.0831x over previous
//
#include <hip/hip_runtime.h>
#include <hip/hip_bf16.h>
#include <math.h>

#define SEQ 512
#define DM 512
#define NH 8
#define DKH 64
#define EPSV 1e-6f
#define LN2F 0.6931471805599453f

typedef __attribute__((ext_vector_type(8))) short short8v;
typedef __attribute__((ext_vector_type(8))) unsigned short ushort8v;
typedef __attribute__((ext_vector_type(16))) float f32x16;

__device__ inline unsigned short f2bf(float x) {
  union { float f; unsigned u; } v; v.f = x;
  unsigned r = v.u + 0x7FFFu + ((v.u >> 16) & 1u);
  return (unsigned short)(r >> 16);
}
__device__ inline float bf2f(unsigned short h) {
  union { float f; unsigned u; } v; v.u = ((unsigned)h) << 16;
  return v.f;
}

// ---------------------------------------------------------------------------
// Kernel C: convert 12 fp32 512x512 matrices (6 X, 6 W) into a 3-level bf16
// split (x = h1 + h2 + h3, representation error ~2^-27 |x|) in fragment-ready
// layout: pack[m][level][panel p][k-octet ko][row r][8 bf16].
// ---------------------------------------------------------------------------
struct ConvArgs { const float* src[12]; };

__global__ __launch_bounds__(256) void convert_kernel(ConvArgs a,
                                                      unsigned short* __restrict__ pack) {
  const int m = blockIdx.x >> 7;                        // matrix 0..11
  const int g = ((blockIdx.x & 127) << 8) + threadIdx.x; // 0..32767
  const int r = g & 31, ko = (g >> 5) & 63, p = g >> 11;
  const float* src = a.src[m] + (p * 32 + r) * DM + ko * 8;
  float4 x0 = *(const float4*)src;
  float4 x1 = *(const float4*)(src + 4);
  float xs[8] = {x0.x, x0.y, x0.z, x0.w, x1.x, x1.y, x1.z, x1.w};
  ushort8v h1, h2, h3;
#pragma unroll
  for (int e = 0; e < 8; ++e) {
    unsigned short a1 = f2bf(xs[e]);
    float r1 = xs[e] - bf2f(a1);
    unsigned short a2 = f2bf(r1);
    float r2 = r1 - bf2f(a2);
    h1[e] = a1; h2[e] = a2; h3[e] = f2bf(r2);
  }
  unsigned short* dh = pack + (size_t)m * 786432 + p * 16384 + ko * 256 + r * 8;
  *(ushort8v*)dh = h1;
  *(ushort8v*)(dh + 262144) = h2;
  *(ushort8v*)(dh + 524288) = h3;
}

// ---------------------------------------------------------------------------
// Kernel P: six 512^3 GEMMs C = X*W^T + b via 3-level bf16 split MFMA.
// Epilogue fuses the prep squaring: p=3,4 -> v^2+eps ; p=5 -> v^2.
// (r8 3D grid restored: the r9 1D XCD swizzle was part of a +6us regression.)
// C/D layout (verified m74/m101): col = lane&31, row = (i&3)+8*(i>>2)+4*(lane>>5).
// ---------------------------------------------------------------------------
struct GemmArgs { const float* bias[6]; float* out[6]; };

__global__ __launch_bounds__(512) void mfma_proj_kernel(const unsigned short* __restrict__ pack,
                                                        GemmArgs ga) {
  const int p = blockIdx.z;
  const int by = blockIdx.y, bx = blockIdx.x;
  const int t = threadIdx.x, l = t & 63, w = t >> 6;
  const int qd = w & 3, kh = w >> 2;
  const int rowblk = qd >> 1, colblk = qd & 1;
  const int r = l & 31, koff = l >> 5;

  const unsigned short* A = pack + (size_t)p * 786432;
  const unsigned short* B = pack + (size_t)(6 + p) * 786432;
  const int pa = by * 2 + rowblk, pb = bx * 2 + colblk;
  const int ko0 = kh * 32 + koff;
  const size_t aoff = (size_t)pa * 16384 + (size_t)ko0 * 256 + r * 8;
  const size_t boff = (size_t)pb * 16384 + (size_t)ko0 * 256 + r * 8;
  const short8v* A1 = (const short8v*)(A + aoff);
  const short8v* A2 = (const short8v*)(A + 262144 + aoff);
  const short8v* A3 = (const short8v*)(A + 524288 + aoff);
  const short8v* B1 = (const short8v*)(B + boff);
  const short8v* B2 = (const short8v*)(B + 262144 + boff);
  const short8v* B3 = (const short8v*)(B + 524288 + boff);

  f32x16 acc = {};
#pragma unroll 2
  for (int s = 0; s < 16; ++s) {
    short8v a1 = A1[(size_t)s * 64];
    short8v a2 = A2[(size_t)s * 64];
    short8v a3 = A3[(size_t)s * 64];
    short8v b1 = B1[(size_t)s * 64];
    short8v b2 = B2[(size_t)s * 64];
    short8v b3 = B3[(size_t)s * 64];
    acc = __builtin_amdgcn_mfma_f32_32x32x16_bf16(a1, b1, acc, 0, 0, 0);
    acc = __builtin_amdgcn_mfma_f32_32x32x16_bf16(a2, b1, acc, 0, 0, 0);
    acc = __builtin_amdgcn_mfma_f32_32x32x16_bf16(a1, b2, acc, 0, 0, 0);
    acc = __builtin_amdgcn_mfma_f32_32x32x16_bf16(a3, b1, acc, 0, 0, 0);
    acc = __builtin_amdgcn_mfma_f32_32x32x16_bf16(a2, b2, acc, 0, 0, 0);
    acc = __builtin_amdgcn_mfma_f32_32x32x16_bf16(a1, b3, acc, 0, 0, 0);
  }

  __shared__ float red[4][32][33];
  if (kh == 1) {
#pragma unroll
    for (int i = 0; i < 16; ++i) {
      int row = (i & 3) + 8 * (i >> 2) + 4 * (l >> 5);
      red[qd][row][r] = acc[i];
    }
  }
  __syncthreads();
  if (kh == 0) {
    const int colg = bx * 64 + colblk * 32 + r;
    const float bias = ga.bias[p][colg];
    float* C = ga.out[p];
    const int rowbase = by * 64 + rowblk * 32;
#pragma unroll
    for (int i = 0; i < 16; ++i) {
      int row = (i & 3) + 8 * (i >> 2) + 4 * (l >> 5);
      float v = acc[i] + red[qd][row][r] + bias;
      if (p >= 3) v = fmaf(v, v, (p == 5) ? 0.f : EPSV);   // fused prep
      C[(size_t)(rowbase + row) * DM + colg] = v;
    }
  }
}

// ---------------------------------------------------------------------------
// Kernel D: distance matrix, causal 64x32 tiles, h = blk/72 (r8 ordering
// restored). Thread = 4q x 2k microtile. Log2 grouped as products of 4
// (log2(s0*s1*s2*s3): 4 O(1)-range factors cannot over/underflow fp32) ->
// 4x fewer v_log_f32. Row log2-sums inline.
// ---------------------------------------------------------------------------
__global__ __launch_bounds__(256) void dist_kernel(const float* __restrict__ aq,
                                                   const float* __restrict__ ak,
                                                   const float* __restrict__ mq,
                                                   const float* __restrict__ mk,
                                                   float* __restrict__ dist) {
  const int blk = blockIdx.x;
  const int h = blk / 72;
  const int tt = blk % 72;
  int qt = (int)sqrtf((float)tt);
  while ((qt + 1) * (qt + 2) <= tt) ++qt;
  while (qt * (qt + 1) > tt) --qt;
  const int kt = tt - qt * (qt + 1);   // 0 .. 2*qt+1

  __shared__ float aqs[64][68], mqs[64][68], aks[32][68], mks[32][68];
  __shared__ float lsum[96][2];
  const int t = threadIdx.x;
#pragma unroll
  for (int i = 0; i < 4; ++i) {
    int idx = t + 256 * i;          // 0..1023: q rows
    int r = idx >> 4, c4 = idx & 15;
    int gq = (qt * 64 + r) * DM + h * 64 + c4 * 4;
    *(float4*)&aqs[r][c4 * 4] = *(const float4*)&aq[gq];
    *(float4*)&mqs[r][c4 * 4] = *(const float4*)&mq[gq];
  }
#pragma unroll
  for (int i = 0; i < 2; ++i) {
    int idx = t + 256 * i;          // 0..511: k rows
    int r = idx >> 4, c4 = idx & 15;
    int gk = (kt * 32 + r) * DM + h * 64 + c4 * 4;
    *(float4*)&aks[r][c4 * 4] = *(const float4*)&ak[gk];
    *(float4*)&mks[r][c4 * 4] = *(const float4*)&mk[gk];
  }
  __syncthreads();

  if (t < 192) {
    int row = t >> 1, par = t & 1;
    const float* src = (row < 64) ? &aqs[row][0] : &aks[row - 64][0];
    float s = 0.f;
#pragma unroll
    for (int d = 0; d < 32; d += 4) {
      float pr = src[par * 32 + d] * src[par * 32 + d + 1]
               * src[par * 32 + d + 2] * src[par * 32 + d + 3];
      s += __log2f(pr);
    }
    lsum[row][par] = s;
  }
  __syncthreads();

  const int tq = t >> 4, tk = t & 15;
  float accl[4][2], acct[4][2];
#pragma unroll
  for (int i = 0; i < 4; ++i)
#pragma unroll
    for (int j = 0; j < 2; ++j) { accl[i][j] = 0.f; acct[i][j] = 0.f; }

#pragma unroll 2
  for (int d4 = 0; d4 < 16; ++d4) {
    float4 qa[4], qm[4], ka[2], km[2];
#pragma unroll
    for (int i = 0; i < 4; ++i) {
      qa[i] = *(const float4*)&aqs[tq * 4 + i][d4 * 4];
      qm[i] = *(const float4*)&mqs[tq * 4 + i][d4 * 4];
    }
#pragma unroll
    for (int j = 0; j < 2; ++j) {
      ka[j] = *(const float4*)&aks[tk + 16 * j][d4 * 4];
      km[j] = *(const float4*)&mks[tk + 16 * j][d4 * 4];
    }
#pragma unroll
    for (int i = 0; i < 4; ++i) {
      float qav[4] = {qa[i].x, qa[i].y, qa[i].z, qa[i].w};
      float qmv[4] = {qm[i].x, qm[i].y, qm[i].z, qm[i].w};
#pragma unroll
      for (int j = 0; j < 2; ++j) {
        float kav[4] = {ka[j].x, ka[j].y, ka[j].z, ka[j].w};
        float kmv[4] = {km[j].x, km[j].y, km[j].z, km[j].w};
        float pr = 1.f;
#pragma unroll
        for (int e = 0; e < 4; ++e) {
          float s = qav[e] + kav[e];
          pr = (e == 0) ? s : pr * s;
          float dm = qmv[e] - kmv[e];
          float rcp = __builtin_amdgcn_rcpf(s - EPSV);
          acct[i][j] = fmaf(dm * dm, rcp, acct[i][j]);
        }
        accl[i][j] += __log2f(pr);
      }
    }
  }

  const int qg0 = qt * 64 + tq * 4;
#pragma unroll
  for (int i = 0; i < 4; ++i) {
    float la2 = lsum[tq * 4 + i][0] + lsum[tq * 4 + i][1];
#pragma unroll
    for (int j = 0; j < 2; ++j) {
      int kg = kt * 32 + tk + 16 * j;
      float lc2 = lsum[64 + tk + 16 * j][0] + lsum[64 + tk + 16 * j][1];
      float dv = (LN2F * (0.5f * accl[i][j] - 0.25f * (la2 + lc2) - 32.f)
                  + 0.25f * acct[i][j]) * 0.125f;
      dist[((size_t)(h * SEQ) + qg0 + i) * SEQ + kg] = dv;
    }
  }
}

// ---------------------------------------------------------------------------
// Kernel S (fused): blocks [0,1024): causal softmax (r8 wid-major ordering),
// lane owns k-octet; fully-masked lanes SKIP the dist load (exec-masked
// loads issue no traffic -> ~half the 8MB re-read). Stores stay
// unconditional (masked lanes write P=0, pv reads full panels).
// aPack is bf16 HI-ONLY. Blocks [1024,1040): pack Vt hi/lo B-fragments.
// ---------------------------------------------------------------------------
__global__ __launch_bounds__(256) void softmax_pvpack_kernel(const float* __restrict__ dist,
                                                             const float* __restrict__ mv,
                                                             const float* __restrict__ sv2,
                                                             unsigned short* __restrict__ aPack,
                                                             unsigned short* __restrict__ vPack) {
  __shared__ float tile[64][65];
  const int t = threadIdx.x;

  if (blockIdx.x < 1024) {
    const int wid = blockIdx.x * 4 + (t >> 6);   // h*512+q
    const int l = t & 63;
    const int h = wid >> 9;
    const int q = wid & 511;
    const float* row = dist + (size_t)wid * SEQ;

    float vals[8];
    float m = -1e30f;
    if (l * 8 <= q) {            // causal skip: masked octets load nothing
      float4 v0 = *(const float4*)&row[l * 8];
      float4 v1 = *(const float4*)&row[l * 8 + 4];
      vals[0] = v0.x; vals[1] = v0.y; vals[2] = v0.z; vals[3] = v0.w;
      vals[4] = v1.x; vals[5] = v1.y; vals[6] = v1.z; vals[7] = v1.w;
#pragma unroll
      for (int e = 0; e < 8; ++e) {
        vals[e] = (l * 8 + e <= q) ? vals[e] : -1e30f;
        m = fmaxf(m, vals[e]);
      }
    } else {
#pragma unroll
      for (int e = 0; e < 8; ++e) vals[e] = -1e30f;
    }
#pragma unroll
    for (int o = 32; o; o >>= 1) m = fmaxf(m, __shfl_xor(m, o, 64));
    float ssum = 0.f;
#pragma unroll
    for (int e = 0; e < 8; ++e) {
      float p = (l * 8 + e <= q) ? __expf(vals[e] - m) : 0.f;
      vals[e] = p;
      ssum += p;
    }
#pragma unroll
    for (int o = 32; o; o >>= 1) ssum += __shfl_xor(ssum, o, 64);
    float rs = 1.f / ssum;

    ushort8v hi;
#pragma unroll
    for (int e = 0; e < 8; ++e) hi[e] = f2bf(vals[e] * rs);
    unsigned short* dst = aPack + (size_t)h * 262144 + (q >> 5) * 16384 + l * 256 + (q & 31) * 8;
    *(ushort8v*)dst = hi;
  } else {
    const int bb = blockIdx.x - 1024;
    const int h = bb >> 1;
    const int mm = bb & 1;
    const float* src = (mm == 0) ? mv : sv2;
    unsigned short* base = vPack + (size_t)(h * 2 + mm) * 65536;

    for (int k0 = 0; k0 < SEQ; k0 += 64) {
      __syncthreads();
#pragma unroll
      for (int i = 0; i < 4; ++i) {
        int idx = t + 256 * i;          // 0..1023
        int r = idx >> 4, c4 = idx & 15;
        float4 v = *(const float4*)&src[(size_t)(k0 + r) * DM + h * 64 + c4 * 4];
        tile[r][c4 * 4 + 0] = v.x; tile[r][c4 * 4 + 1] = v.y;
        tile[r][c4 * 4 + 2] = v.z; tile[r][c4 * 4 + 3] = v.w;
      }
      __syncthreads();
#pragma unroll
      for (int i = 0; i < 2; ++i) {
        int idx = t + 256 * i;          // 0..511
        int d = idx & 63, ko = idx >> 6;
        ushort8v hi, lo;
#pragma unroll
        for (int e = 0; e < 8; ++e) {
          float x = tile[ko * 8 + e][d];
          unsigned short hh = f2bf(x);
          hi[e] = hh;
          lo[e] = f2bf(x - bf2f(hh));
        }
        int koG = (k0 >> 3) + ko;
        unsigned short* dst = base + (d >> 5) * 16384 + koG * 256 + (d & 31) * 8;
        *(ushort8v*)dst = hi;
        *(ushort8v*)(dst + 32768) = lo;
      }
    }
  }
}

// ---------------------------------------------------------------------------
// Kernel V: PV via MFMA, P hi-only: 2 MFMAs per K=16 step (a1b1 + a1b2).
// r8 block mapping (h = blk>>4). Block = (h, 32-row q-tile); 4 waves:
// wave w -> (d-tile = w&1, matrix = w>>1). Causal k-steps only.
// ---------------------------------------------------------------------------
__global__ __launch_bounds__(256) void pv_mfma_kernel(const unsigned short* __restrict__ aPack,
                                                      const unsigned short* __restrict__ vPack,
                                                      float* __restrict__ out) {
  const int h = blockIdx.x >> 4;
  const int qt = blockIdx.x & 15;
  const int t = threadIdx.x, l = t & 63, w = t >> 6;
  const int dt = w & 1, mm = w >> 1;

  const unsigned short* aBase = aPack + (size_t)h * 262144 + qt * 16384
                                + (l >> 5) * 256 + (l & 31) * 8;
  const unsigned short* vBase = vPack + (size_t)(h * 2 + mm) * 65536 + dt * 16384
                                + (l >> 5) * 256 + (l & 31) * 8;

  f32x16 acc = {};
  const int nks = 2 * qt + 2;   // K=16 steps covering k <= qt*32+31
#pragma unroll 2
  for (int s = 0; s < nks; ++s) {
    short8v a1 = *(const short8v*)(aBase + (size_t)s * 512);
    short8v b1 = *(const short8v*)(vBase + (size_t)s * 512);
    short8v b2 = *(const short8v*)(vBase + 32768 + (size_t)s * 512);
    acc = __builtin_amdgcn_mfma_f32_32x32x16_bf16(a1, b1, acc, 0, 0, 0);
    acc = __builtin_amdgcn_mfma_f32_32x32x16_bf16(a1, b2, acc, 0, 0, 0);
  }

  float* dst = out + ((mm == 0) ? 0 : (size_t)NH * SEQ * DKH);
  const int col = dt * 32 + (l & 31);
#pragma unroll
  for (int i = 0; i < 16; ++i) {
    int qrow = (i & 3) + 8 * (i >> 2) + 4 * (l >> 5);
    int q = qt * 32 + qrow;
    float v = acc[i];
    if (mm) v = sqrtf(fmaxf(v, 0.f) + EPSV);
    dst[((size_t)h * SEQ + q) * DKH + col] = v;
  }
}

// ---------------------------------------------------------------------------
extern "C" void kernel_launch(void* const* d_in, const int* in_sizes, int n_in,
                              void* d_out, int out_size, void* d_ws, size_t ws_size,
                              hipStream_t stream) {
  (void)in_sizes; (void)n_in; (void)out_size; (void)ws_size;

  float* ws = (float*)d_ws;
  float* mq = ws;                 // 512*512 each
  float* mk = mq + 262144;
  float* mv = mk + 262144;
  float* sq = mv + 262144;        // aq = sigma_q^2 + eps (proj epilogue)
  float* sk = sq + 262144;        // ak = sigma_k^2 + eps
  float* sv = sk + 262144;        // sv^2
  // pack region: 12 x 3 levels x 512KB = 18 MB, dead after the proj GEMM.
  // Reused as: dist (8 MB) + aPack hi-only (4 MB) + vPack (2 MB).
  unsigned short* pack = (unsigned short*)(sv + 262144);
  float* dist = (float*)pack;                         // [0, 8MB)
  unsigned short* aPack = pack + 4194304;             // [8MB, 12MB)
  unsigned short* vPack = pack + 6291456;             // [12MB, 14MB)

  ConvArgs ca;
  ca.src[0] = (const float*)d_in[0];
  ca.src[1] = (const float*)d_in[1];
  ca.src[2] = (const float*)d_in[2];
  ca.src[3] = (const float*)d_in[3];
  ca.src[4] = (const float*)d_in[4];
  ca.src[5] = (const float*)d_in[5];
  ca.src[6] = (const float*)d_in[6];
  ca.src[7] = (const float*)d_in[8];
  ca.src[8] = (const float*)d_in[10];
  ca.src[9] = (const float*)d_in[12];
  ca.src[10] = (const float*)d_in[14];
  ca.src[11] = (const float*)d_in[16];

  GemmArgs gaArgs;
  gaArgs.bias[0] = (const float*)d_in[7];  gaArgs.out[0] = mq;
  gaArgs.bias[1] = (const float*)d_in[9];  gaArgs.out[1] = mk;
  gaArgs.bias[2] = (const float*)d_in[11]; gaArgs.out[2] = mv;
  gaArgs.bias[3] = (const float*)d_in[13]; gaArgs.out[3] = sq;
  gaArgs.bias[4] = (const float*)d_in[15]; gaArgs.out[4] = sk;
  gaArgs.bias[5] = (const float*)d_in[17]; gaArgs.out[5] = sv;

  convert_kernel<<<12 * 128, 256, 0, stream>>>(ca, pack);

  dim3 ggrid(8, 8, 6);
  mfma_proj_kernel<<<ggrid, 512, 0, stream>>>(pack, gaArgs);

  dist_kernel<<<8 * 72, 256, 0, stream>>>(sq, sk, mq, mk, dist);

  softmax_pvpack_kernel<<<1040, 256, 0, stream>>>(dist, mv, sv, aPack, vPack);

  pv_mfma_kernel<<<128, 256, 0, stream>>>(aPack, vPack, (float*)d_out);
}

// Round 11
// 154.578 us; speedup vs baseline: 1.1196x; 1.0337x over previous
//
#include <hip/hip_runtime.h>
#include <hip/hip_bf16.h>
#include <math.h>

#define SEQ 512
#define DM 512
#define NH 8
#define DKH 64
#define EPSV 1e-6f
#define LN2F 0.6931471805599453f

typedef __attribute__((ext_vector_type(8))) short short8v;
typedef __attribute__((ext_vector_type(8))) unsigned short ushort8v;
typedef __attribute__((ext_vector_type(4))) unsigned short ushort4v;
typedef __attribute__((ext_vector_type(16))) float f32x16;

__device__ inline unsigned short f2bf(float x) {
  union { float f; unsigned u; } v; v.f = x;
  unsigned r = v.u + 0x7FFFu + ((v.u >> 16) & 1u);
  return (unsigned short)(r >> 16);
}
__device__ inline float bf2f(unsigned short h) {
  union { float f; unsigned u; } v; v.u = ((unsigned)h) << 16;
  return v.f;
}

// ---------------------------------------------------------------------------
// Kernel C: convert 12 fp32 512x512 matrices into 3-level bf16 splits in
// fragment-ready layout pack[m][level][panel][k-octet][row][8].
// m in {2,5,8,11} (value / value_sigma / wv_mu / wv_s) feed only the 2-level
// GEMMs (p=2,5) -> skip the h3 store for those.
// ---------------------------------------------------------------------------
struct ConvArgs { const float* src[12]; };

__global__ __launch_bounds__(256) void convert_kernel(ConvArgs a,
                                                      unsigned short* __restrict__ pack) {
  const int m = blockIdx.x >> 7;                        // matrix 0..11
  const int g = ((blockIdx.x & 127) << 8) + threadIdx.x; // 0..32767
  const int r = g & 31, ko = (g >> 5) & 63, p = g >> 11;
  const float* src = a.src[m] + (p * 32 + r) * DM + ko * 8;
  float4 x0 = *(const float4*)src;
  float4 x1 = *(const float4*)(src + 4);
  float xs[8] = {x0.x, x0.y, x0.z, x0.w, x1.x, x1.y, x1.z, x1.w};
  ushort8v h1, h2, h3;
#pragma unroll
  for (int e = 0; e < 8; ++e) {
    unsigned short a1 = f2bf(xs[e]);
    float r1 = xs[e] - bf2f(a1);
    unsigned short a2 = f2bf(r1);
    float r2 = r1 - bf2f(a2);
    h1[e] = a1; h2[e] = a2; h3[e] = f2bf(r2);
  }
  unsigned short* dh = pack + (size_t)m * 786432 + p * 16384 + ko * 256 + r * 8;
  *(ushort8v*)dh = h1;
  *(ushort8v*)(dh + 262144) = h2;
  const bool two_level = (m == 2) || (m == 5) || (m == 8) || (m == 11);
  if (!two_level) *(ushort8v*)(dh + 524288) = h3;
}

// ---------------------------------------------------------------------------
// Kernel P: six 512^3 GEMMs C = X*W^T + b via bf16-split MFMA.
// p in {0,1,3,4}: 3-level, 6 MFMAs/step (sigma/mu feed the 1/(a+c)-sensitive
// dist path). p in {2,5}: 2-level, 3 MFMAs/step (linear PV path, 2^-17 ok);
// these skip the C store and instead emit vPack hi/lo B-fragments directly
// from the epilogue (bx == head since DKH == 64) -> pvpack pass eliminated.
// Epilogue fuses prep squaring: p=3,4 -> v^2+eps ; p=5 -> v^2.
// C/D layout (verified m74/m101): col = lane&31, row = (i&3)+8*(i>>2)+4*(lane>>5).
// ---------------------------------------------------------------------------
struct GemmArgs { const float* bias[6]; float* out[6]; unsigned short* vPack; };

__global__ __launch_bounds__(512) void mfma_proj_kernel(const unsigned short* __restrict__ pack,
                                                        GemmArgs ga) {
  const int p = blockIdx.z;
  const int by = blockIdx.y, bx = blockIdx.x;
  const int t = threadIdx.x, l = t & 63, w = t >> 6;
  const int qd = w & 3, kh = w >> 2;
  const int rowblk = qd >> 1, colblk = qd & 1;
  const int r = l & 31, koff = l >> 5;

  const unsigned short* A = pack + (size_t)p * 786432;
  const unsigned short* B = pack + (size_t)(6 + p) * 786432;
  const int pa = by * 2 + rowblk, pb = bx * 2 + colblk;
  const int ko0 = kh * 32 + koff;
  const size_t aoff = (size_t)pa * 16384 + (size_t)ko0 * 256 + r * 8;
  const size_t boff = (size_t)pb * 16384 + (size_t)ko0 * 256 + r * 8;
  const short8v* A1 = (const short8v*)(A + aoff);
  const short8v* A2 = (const short8v*)(A + 262144 + aoff);
  const short8v* A3 = (const short8v*)(A + 524288 + aoff);
  const short8v* B1 = (const short8v*)(B + boff);
  const short8v* B2 = (const short8v*)(B + 262144 + boff);
  const short8v* B3 = (const short8v*)(B + 524288 + boff);

  const bool lite = (p == 2) || (p == 5);
  f32x16 acc = {};
  if (lite) {
#pragma unroll 2
    for (int s = 0; s < 16; ++s) {
      short8v a1 = A1[(size_t)s * 64];
      short8v a2 = A2[(size_t)s * 64];
      short8v b1 = B1[(size_t)s * 64];
      short8v b2 = B2[(size_t)s * 64];
      acc = __builtin_amdgcn_mfma_f32_32x32x16_bf16(a1, b1, acc, 0, 0, 0);
      acc = __builtin_amdgcn_mfma_f32_32x32x16_bf16(a2, b1, acc, 0, 0, 0);
      acc = __builtin_amdgcn_mfma_f32_32x32x16_bf16(a1, b2, acc, 0, 0, 0);
    }
  } else {
#pragma unroll 2
    for (int s = 0; s < 16; ++s) {
      short8v a1 = A1[(size_t)s * 64];
      short8v a2 = A2[(size_t)s * 64];
      short8v a3 = A3[(size_t)s * 64];
      short8v b1 = B1[(size_t)s * 64];
      short8v b2 = B2[(size_t)s * 64];
      short8v b3 = B3[(size_t)s * 64];
      acc = __builtin_amdgcn_mfma_f32_32x32x16_bf16(a1, b1, acc, 0, 0, 0);
      acc = __builtin_amdgcn_mfma_f32_32x32x16_bf16(a2, b1, acc, 0, 0, 0);
      acc = __builtin_amdgcn_mfma_f32_32x32x16_bf16(a1, b2, acc, 0, 0, 0);
      acc = __builtin_amdgcn_mfma_f32_32x32x16_bf16(a3, b1, acc, 0, 0, 0);
      acc = __builtin_amdgcn_mfma_f32_32x32x16_bf16(a2, b2, acc, 0, 0, 0);
      acc = __builtin_amdgcn_mfma_f32_32x32x16_bf16(a1, b3, acc, 0, 0, 0);
    }
  }

  __shared__ float red[4][32][33];
  if (kh == 1) {
#pragma unroll
    for (int i = 0; i < 16; ++i) {
      int row = (i & 3) + 8 * (i >> 2) + 4 * (l >> 5);
      red[qd][row][r] = acc[i];
    }
  }
  __syncthreads();
  if (kh == 0) {
    const int colg = bx * 64 + colblk * 32 + r;
    const float bias = ga.bias[p][colg];
    const int rowbase = by * 64 + rowblk * 32;
    if (lite) {
      // vPack[(h,mm)][level][pd=d>>5][ko][d&31][k&7]; h = bx, d = colblk*32+r,
      // thread's 16 acc rows = rowbase + (i&3)+8*(i>>2)+4*(l>>5) -> per group
      // g=(i>>2): octet ko0v+g, lanes fill (k&7) = (l>>5)*4 + (i&3).
      const int mm = (p == 5);
      unsigned short* vb = ga.vPack + (size_t)(bx * 2 + mm) * 65536
                         + colblk * 16384 + (rowbase >> 3) * 256 + r * 8 + (l >> 5) * 4;
#pragma unroll
      for (int g = 0; g < 4; ++g) {
        ushort4v hi4, lo4;
#pragma unroll
        for (int e = 0; e < 4; ++e) {
          int i = g * 4 + e;
          int row = (i & 3) + 8 * (i >> 2) + 4 * (l >> 5);
          float v = acc[i] + red[qd][row][r] + bias;
          if (p == 5) v = v * v;
          unsigned short hh = f2bf(v);
          hi4[e] = hh;
          lo4[e] = f2bf(v - bf2f(hh));
        }
        *(ushort4v*)(vb + g * 256) = hi4;
        *(ushort4v*)(vb + 32768 + g * 256) = lo4;
      }
    } else {
      float* C = ga.out[p];
#pragma unroll
      for (int i = 0; i < 16; ++i) {
        int row = (i & 3) + 8 * (i >> 2) + 4 * (l >> 5);
        float v = acc[i] + red[qd][row][r] + bias;
        if (p >= 3) v = fmaf(v, v, EPSV);   // fused prep (p=3,4)
        C[(size_t)(rowbase + row) * DM + colg] = v;
      }
    }
  }
}

// ---------------------------------------------------------------------------
// Kernel D: distance matrix, causal 64x32 tiles, h = blk/72.
// Thread = 4q x 2k microtile. Log2 grouped as products of 4 (4 O(1)-range
// factors cannot over/underflow fp32) -> 4x fewer v_log_f32. Inline row sums.
// ---------------------------------------------------------------------------
__global__ __launch_bounds__(256) void dist_kernel(const float* __restrict__ aq,
                                                   const float* __restrict__ ak,
                                                   const float* __restrict__ mq,
                                                   const float* __restrict__ mk,
                                                   float* __restrict__ dist) {
  const int blk = blockIdx.x;
  const int h = blk / 72;
  const int tt = blk % 72;
  int qt = (int)sqrtf((float)tt);
  while ((qt + 1) * (qt + 2) <= tt) ++qt;
  while (qt * (qt + 1) > tt) --qt;
  const int kt = tt - qt * (qt + 1);   // 0 .. 2*qt+1

  __shared__ float aqs[64][68], mqs[64][68], aks[32][68], mks[32][68];
  __shared__ float lsum[96][2];
  const int t = threadIdx.x;
#pragma unroll
  for (int i = 0; i < 4; ++i) {
    int idx = t + 256 * i;          // 0..1023: q rows
    int r = idx >> 4, c4 = idx & 15;
    int gq = (qt * 64 + r) * DM + h * 64 + c4 * 4;
    *(float4*)&aqs[r][c4 * 4] = *(const float4*)&aq[gq];
    *(float4*)&mqs[r][c4 * 4] = *(const float4*)&mq[gq];
  }
#pragma unroll
  for (int i = 0; i < 2; ++i) {
    int idx = t + 256 * i;          // 0..511: k rows
    int r = idx >> 4, c4 = idx & 15;
    int gk = (kt * 32 + r) * DM + h * 64 + c4 * 4;
    *(float4*)&aks[r][c4 * 4] = *(const float4*)&ak[gk];
    *(float4*)&mks[r][c4 * 4] = *(const float4*)&mk[gk];
  }
  __syncthreads();

  if (t < 192) {
    int row = t >> 1, par = t & 1;
    const float* src = (row < 64) ? &aqs[row][0] : &aks[row - 64][0];
    float s = 0.f;
#pragma unroll
    for (int d = 0; d < 32; d += 4) {
      float pr = src[par * 32 + d] * src[par * 32 + d + 1]
               * src[par * 32 + d + 2] * src[par * 32 + d + 3];
      s += __log2f(pr);
    }
    lsum[row][par] = s;
  }
  __syncthreads();

  const int tq = t >> 4, tk = t & 15;
  float accl[4][2], acct[4][2];
#pragma unroll
  for (int i = 0; i < 4; ++i)
#pragma unroll
    for (int j = 0; j < 2; ++j) { accl[i][j] = 0.f; acct[i][j] = 0.f; }

#pragma unroll 2
  for (int d4 = 0; d4 < 16; ++d4) {
    float4 qa[4], qm[4], ka[2], km[2];
#pragma unroll
    for (int i = 0; i < 4; ++i) {
      qa[i] = *(const float4*)&aqs[tq * 4 + i][d4 * 4];
      qm[i] = *(const float4*)&mqs[tq * 4 + i][d4 * 4];
    }
#pragma unroll
    for (int j = 0; j < 2; ++j) {
      ka[j] = *(const float4*)&aks[tk + 16 * j][d4 * 4];
      km[j] = *(const float4*)&mks[tk + 16 * j][d4 * 4];
    }
#pragma unroll
    for (int i = 0; i < 4; ++i) {
      float qav[4] = {qa[i].x, qa[i].y, qa[i].z, qa[i].w};
      float qmv[4] = {qm[i].x, qm[i].y, qm[i].z, qm[i].w};
#pragma unroll
      for (int j = 0; j < 2; ++j) {
        float kav[4] = {ka[j].x, ka[j].y, ka[j].z, ka[j].w};
        float kmv[4] = {km[j].x, km[j].y, km[j].z, km[j].w};
        float pr = 1.f;
#pragma unroll
        for (int e = 0; e < 4; ++e) {
          float s = qav[e] + kav[e];
          pr = (e == 0) ? s : pr * s;
          float dm = qmv[e] - kmv[e];
          float rcp = __builtin_amdgcn_rcpf(s - EPSV);
          acct[i][j] = fmaf(dm * dm, rcp, acct[i][j]);
        }
        accl[i][j] += __log2f(pr);
      }
    }
  }

  const int qg0 = qt * 64 + tq * 4;
#pragma unroll
  for (int i = 0; i < 4; ++i) {
    float la2 = lsum[tq * 4 + i][0] + lsum[tq * 4 + i][1];
#pragma unroll
    for (int j = 0; j < 2; ++j) {
      int kg = kt * 32 + tk + 16 * j;
      float lc2 = lsum[64 + tk + 16 * j][0] + lsum[64 + tk + 16 * j][1];
      float dv = (LN2F * (0.5f * accl[i][j] - 0.25f * (la2 + lc2) - 32.f)
                  + 0.25f * acct[i][j]) * 0.125f;
      dist[((size_t)(h * SEQ) + qg0 + i) * SEQ + kg] = dv;
    }
  }
}

// ---------------------------------------------------------------------------
// Kernel S: causal softmax only (vPack moved into proj). Lane owns k-octet;
// fully-masked lanes skip the dist load. aPack is bf16 HI-ONLY.
// ---------------------------------------------------------------------------
__global__ __launch_bounds__(256) void softmax_kernel(const float* __restrict__ dist,
                                                      unsigned short* __restrict__ aPack) {
  const int t = threadIdx.x;
  const int wid = blockIdx.x * 4 + (t >> 6);   // h*512+q
  const int l = t & 63;
  const int h = wid >> 9;
  const int q = wid & 511;
  const float* row = dist + (size_t)wid * SEQ;

  float vals[8];
  float m = -1e30f;
  if (l * 8 <= q) {            // causal skip: masked octets load nothing
    float4 v0 = *(const float4*)&row[l * 8];
    float4 v1 = *(const float4*)&row[l * 8 + 4];
    vals[0] = v0.x; vals[1] = v0.y; vals[2] = v0.z; vals[3] = v0.w;
    vals[4] = v1.x; vals[5] = v1.y; vals[6] = v1.z; vals[7] = v1.w;
#pragma unroll
    for (int e = 0; e < 8; ++e) {
      vals[e] = (l * 8 + e <= q) ? vals[e] : -1e30f;
      m = fmaxf(m, vals[e]);
    }
  } else {
#pragma unroll
    for (int e = 0; e < 8; ++e) vals[e] = -1e30f;
  }
#pragma unroll
  for (int o = 32; o; o >>= 1) m = fmaxf(m, __shfl_xor(m, o, 64));
  float ssum = 0.f;
#pragma unroll
  for (int e = 0; e < 8; ++e) {
    float p = (l * 8 + e <= q) ? __expf(vals[e] - m) : 0.f;
    vals[e] = p;
    ssum += p;
  }
#pragma unroll
  for (int o = 32; o; o >>= 1) ssum += __shfl_xor(ssum, o, 64);
  float rs = 1.f / ssum;

  ushort8v hi;
#pragma unroll
  for (int e = 0; e < 8; ++e) hi[e] = f2bf(vals[e] * rs);
  unsigned short* dst = aPack + (size_t)h * 262144 + (q >> 5) * 16384 + l * 256 + (q & 31) * 8;
  *(ushort8v*)dst = hi;
}

// ---------------------------------------------------------------------------
// Kernel V: PV via MFMA, P hi-only: 2 MFMAs per K=16 step (a1b1 + a1b2).
// Grid 256 x 128 threads (mm in blockIdx) -> all 256 CUs active (the 128-block
// version left half the chip idle). Causal k-steps only.
// ---------------------------------------------------------------------------
__global__ __launch_bounds__(128) void pv_mfma_kernel(const unsigned short* __restrict__ aPack,
                                                      const unsigned short* __restrict__ vPack,
                                                      float* __restrict__ out) {
  const int b = blockIdx.x;         // h*32 + qt*2 + mm
  const int h = b >> 5;
  const int qt = (b >> 1) & 15;
  const int mm = b & 1;
  const int t = threadIdx.x, l = t & 63;
  const int dt = t >> 6;            // wave id 0/1 -> d-tile

  const unsigned short* aBase = aPack + (size_t)h * 262144 + qt * 16384
                                + (l >> 5) * 256 + (l & 31) * 8;
  const unsigned short* vBase = vPack + (size_t)(h * 2 + mm) * 65536 + dt * 16384
                                + (l >> 5) * 256 + (l & 31) * 8;

  f32x16 acc = {};
  const int nks = 2 * qt + 2;   // K=16 steps covering k <= qt*32+31
#pragma unroll 2
  for (int s = 0; s < nks; ++s) {
    short8v a1 = *(const short8v*)(aBase + (size_t)s * 512);
    short8v b1 = *(const short8v*)(vBase + (size_t)s * 512);
    short8v b2 = *(const short8v*)(vBase + 32768 + (size_t)s * 512);
    acc = __builtin_amdgcn_mfma_f32_32x32x16_bf16(a1, b1, acc, 0, 0, 0);
    acc = __builtin_amdgcn_mfma_f32_32x32x16_bf16(a1, b2, acc, 0, 0, 0);
  }

  float* dst = out + ((mm == 0) ? 0 : (size_t)NH * SEQ * DKH);
  const int col = dt * 32 + (l & 31);
#pragma unroll
  for (int i = 0; i < 16; ++i) {
    int qrow = (i & 3) + 8 * (i >> 2) + 4 * (l >> 5);
    int q = qt * 32 + qrow;
    float v = acc[i];
    if (mm) v = sqrtf(fmaxf(v, 0.f) + EPSV);
    dst[((size_t)h * SEQ + q) * DKH + col] = v;
  }
}

// ---------------------------------------------------------------------------
extern "C" void kernel_launch(void* const* d_in, const int* in_sizes, int n_in,
                              void* d_out, int out_size, void* d_ws, size_t ws_size,
                              hipStream_t stream) {
  (void)in_sizes; (void)n_in; (void)out_size; (void)ws_size;

  float* ws = (float*)d_ws;
  float* mq = ws;                 // 512*512 each
  float* mk = mq + 262144;
  float* mv = mk + 262144;        // unused (p=2 emits vPack directly)
  float* sq = mv + 262144;        // aq = sigma_q^2 + eps (proj epilogue)
  float* sk = sq + 262144;        // ak = sigma_k^2 + eps
  float* sv = sk + 262144;        // unused (p=5 emits vPack directly)
  // pack region: 18 MB, dead after the proj GEMM; dist (8 MB) + aPack (4 MB)
  // alias it. vPack must live OUTSIDE pack (proj writes it while reading
  // pack m=8 at +12MB) -> placed after the 18 MB region.
  unsigned short* pack = (unsigned short*)(sv + 262144);
  float* dist = (float*)pack;                         // [0, 8MB)
  unsigned short* aPack = pack + 4194304;             // [8MB, 12MB)
  unsigned short* vPack = pack + 9437184;             // [18MB, 20MB)

  ConvArgs ca;
  ca.src[0] = (const float*)d_in[0];
  ca.src[1] = (const float*)d_in[1];
  ca.src[2] = (const float*)d_in[2];
  ca.src[3] = (const float*)d_in[3];
  ca.src[4] = (const float*)d_in[4];
  ca.src[5] = (const float*)d_in[5];
  ca.src[6] = (const float*)d_in[6];
  ca.src[7] = (const float*)d_in[8];
  ca.src[8] = (const float*)d_in[10];
  ca.src[9] = (const float*)d_in[12];
  ca.src[10] = (const float*)d_in[14];
  ca.src[11] = (const float*)d_in[16];

  GemmArgs gaArgs;
  gaArgs.bias[0] = (const float*)d_in[7];  gaArgs.out[0] = mq;
  gaArgs.bias[1] = (const float*)d_in[9];  gaArgs.out[1] = mk;
  gaArgs.bias[2] = (const float*)d_in[11]; gaArgs.out[2] = mv;
  gaArgs.bias[3] = (const float*)d_in[13]; gaArgs.out[3] = sq;
  gaArgs.bias[4] = (const float*)d_in[15]; gaArgs.out[4] = sk;
  gaArgs.bias[5] = (const float*)d_in[17]; gaArgs.out[5] = sv;
  gaArgs.vPack = vPack;

  convert_kernel<<<12 * 128, 256, 0, stream>>>(ca, pack);

  dim3 ggrid(8, 8, 6);
  mfma_proj_kernel<<<ggrid, 512, 0, stream>>>(pack, gaArgs);

  dist_kernel<<<8 * 72, 256, 0, stream>>>(sq, sk, mq, mk, dist);

  softmax_kernel<<<1024, 256, 0, stream>>>(dist, aPack);

  pv_mfma_kernel<<<256, 128, 0, stream>>>(aPack, vPack, (float*)d_out);
}

// Round 12
// 152.522 us; speedup vs baseline: 1.1347x; 1.0135x over previous
//
#include <hip/hip_runtime.h>
#include <hip/hip_bf16.h>
#include <math.h>

#define SEQ 512
#define DM 512
#define NH 8
#define DKH 64
#define EPSV 1e-6f
#define LN2F 0.6931471805599453f

typedef __attribute__((ext_vector_type(8))) short short8v;
typedef __attribute__((ext_vector_type(8))) unsigned short ushort8v;
typedef __attribute__((ext_vector_type(4))) unsigned short ushort4v;
typedef __attribute__((ext_vector_type(16))) float f32x16;

__device__ inline unsigned short f2bf(float x) {
  union { float f; unsigned u; } v; v.f = x;
  unsigned r = v.u + 0x7FFFu + ((v.u >> 16) & 1u);
  return (unsigned short)(r >> 16);
}
__device__ inline float bf2f(unsigned short h) {
  union { float f; unsigned u; } v; v.u = ((unsigned)h) << 16;
  return v.f;
}

// ---------------------------------------------------------------------------
// Kernel C: convert 12 fp32 512x512 matrices into 3-level bf16 splits in
// fragment-ready layout pack[m][level][panel][k-octet][row][8].
// m in {2,5,8,11} (value / value_sigma / wv_mu / wv_s) feed only the 2-level
// GEMMs (p=2,5) -> skip the h3 store for those.
// ---------------------------------------------------------------------------
struct ConvArgs { const float* src[12]; };

__global__ __launch_bounds__(256) void convert_kernel(ConvArgs a,
                                                      unsigned short* __restrict__ pack) {
  const int m = blockIdx.x >> 7;                        // matrix 0..11
  const int g = ((blockIdx.x & 127) << 8) + threadIdx.x; // 0..32767
  const int r = g & 31, ko = (g >> 5) & 63, p = g >> 11;
  const float* src = a.src[m] + (p * 32 + r) * DM + ko * 8;
  float4 x0 = *(const float4*)src;
  float4 x1 = *(const float4*)(src + 4);
  float xs[8] = {x0.x, x0.y, x0.z, x0.w, x1.x, x1.y, x1.z, x1.w};
  ushort8v h1, h2, h3;
#pragma unroll
  for (int e = 0; e < 8; ++e) {
    unsigned short a1 = f2bf(xs[e]);
    float r1 = xs[e] - bf2f(a1);
    unsigned short a2 = f2bf(r1);
    float r2 = r1 - bf2f(a2);
    h1[e] = a1; h2[e] = a2; h3[e] = f2bf(r2);
  }
  unsigned short* dh = pack + (size_t)m * 786432 + p * 16384 + ko * 256 + r * 8;
  *(ushort8v*)dh = h1;
  *(ushort8v*)(dh + 262144) = h2;
  const bool two_level = (m == 2) || (m == 5) || (m == 8) || (m == 11);
  if (!two_level) *(ushort8v*)(dh + 524288) = h3;
}

// ---------------------------------------------------------------------------
// Kernel P: six 512^3 GEMMs C = X*W^T + b via bf16-split MFMA.
// p in {0,1,3,4}: 3-level, 6 MFMAs/step (sigma/mu feed the 1/(a+c)-sensitive
// dist path). p in {2,5}: 2-level, 3 MFMAs/step (linear PV path, 2^-17 ok);
// these skip the C store and instead emit vPack hi/lo B-fragments directly
// from the epilogue (bx == head since DKH == 64) -> pvpack pass eliminated.
// Epilogue fuses prep squaring: p=3,4 -> v^2+eps ; p=5 -> v^2.
// C/D layout (verified m74/m101): col = lane&31, row = (i&3)+8*(i>>2)+4*(lane>>5).
// ---------------------------------------------------------------------------
struct GemmArgs { const float* bias[6]; float* out[6]; unsigned short* vPack; };

__global__ __launch_bounds__(512) void mfma_proj_kernel(const unsigned short* __restrict__ pack,
                                                        GemmArgs ga) {
  const int p = blockIdx.z;
  const int by = blockIdx.y, bx = blockIdx.x;
  const int t = threadIdx.x, l = t & 63, w = t >> 6;
  const int qd = w & 3, kh = w >> 2;
  const int rowblk = qd >> 1, colblk = qd & 1;
  const int r = l & 31, koff = l >> 5;

  const unsigned short* A = pack + (size_t)p * 786432;
  const unsigned short* B = pack + (size_t)(6 + p) * 786432;
  const int pa = by * 2 + rowblk, pb = bx * 2 + colblk;
  const int ko0 = kh * 32 + koff;
  const size_t aoff = (size_t)pa * 16384 + (size_t)ko0 * 256 + r * 8;
  const size_t boff = (size_t)pb * 16384 + (size_t)ko0 * 256 + r * 8;
  const short8v* A1 = (const short8v*)(A + aoff);
  const short8v* A2 = (const short8v*)(A + 262144 + aoff);
  const short8v* A3 = (const short8v*)(A + 524288 + aoff);
  const short8v* B1 = (const short8v*)(B + boff);
  const short8v* B2 = (const short8v*)(B + 262144 + boff);
  const short8v* B3 = (const short8v*)(B + 524288 + boff);

  const bool lite = (p == 2) || (p == 5);
  f32x16 acc = {};
  if (lite) {
#pragma unroll 2
    for (int s = 0; s < 16; ++s) {
      short8v a1 = A1[(size_t)s * 64];
      short8v a2 = A2[(size_t)s * 64];
      short8v b1 = B1[(size_t)s * 64];
      short8v b2 = B2[(size_t)s * 64];
      acc = __builtin_amdgcn_mfma_f32_32x32x16_bf16(a1, b1, acc, 0, 0, 0);
      acc = __builtin_amdgcn_mfma_f32_32x32x16_bf16(a2, b1, acc, 0, 0, 0);
      acc = __builtin_amdgcn_mfma_f32_32x32x16_bf16(a1, b2, acc, 0, 0, 0);
    }
  } else {
#pragma unroll 2
    for (int s = 0; s < 16; ++s) {
      short8v a1 = A1[(size_t)s * 64];
      short8v a2 = A2[(size_t)s * 64];
      short8v a3 = A3[(size_t)s * 64];
      short8v b1 = B1[(size_t)s * 64];
      short8v b2 = B2[(size_t)s * 64];
      short8v b3 = B3[(size_t)s * 64];
      acc = __builtin_amdgcn_mfma_f32_32x32x16_bf16(a1, b1, acc, 0, 0, 0);
      acc = __builtin_amdgcn_mfma_f32_32x32x16_bf16(a2, b1, acc, 0, 0, 0);
      acc = __builtin_amdgcn_mfma_f32_32x32x16_bf16(a1, b2, acc, 0, 0, 0);
      acc = __builtin_amdgcn_mfma_f32_32x32x16_bf16(a3, b1, acc, 0, 0, 0);
      acc = __builtin_amdgcn_mfma_f32_32x32x16_bf16(a2, b2, acc, 0, 0, 0);
      acc = __builtin_amdgcn_mfma_f32_32x32x16_bf16(a1, b3, acc, 0, 0, 0);
    }
  }

  __shared__ float red[4][32][33];
  if (kh == 1) {
#pragma unroll
    for (int i = 0; i < 16; ++i) {
      int row = (i & 3) + 8 * (i >> 2) + 4 * (l >> 5);
      red[qd][row][r] = acc[i];
    }
  }
  __syncthreads();
  if (kh == 0) {
    const int colg = bx * 64 + colblk * 32 + r;
    const float bias = ga.bias[p][colg];
    const int rowbase = by * 64 + rowblk * 32;
    if (lite) {
      const int mm = (p == 5);
      unsigned short* vb = ga.vPack + (size_t)(bx * 2 + mm) * 65536
                         + colblk * 16384 + (rowbase >> 3) * 256 + r * 8 + (l >> 5) * 4;
#pragma unroll
      for (int g = 0; g < 4; ++g) {
        ushort4v hi4, lo4;
#pragma unroll
        for (int e = 0; e < 4; ++e) {
          int i = g * 4 + e;
          int row = (i & 3) + 8 * (i >> 2) + 4 * (l >> 5);
          float v = acc[i] + red[qd][row][r] + bias;
          if (p == 5) v = v * v;
          unsigned short hh = f2bf(v);
          hi4[e] = hh;
          lo4[e] = f2bf(v - bf2f(hh));
        }
        *(ushort4v*)(vb + g * 256) = hi4;
        *(ushort4v*)(vb + 32768 + g * 256) = lo4;
      }
    } else {
      float* C = ga.out[p];
#pragma unroll
      for (int i = 0; i < 16; ++i) {
        int row = (i & 3) + 8 * (i >> 2) + 4 * (l >> 5);
        float v = acc[i] + red[qd][row][r] + bias;
        if (p >= 3) v = fmaf(v, v, EPSV);   // fused prep (p=3,4)
        C[(size_t)(rowbase + row) * DM + colg] = v;
      }
    }
  }
}

// ---------------------------------------------------------------------------
// Kernel D: distance matrix, causal 64x32 tiles, h = blk/72.
// Thread = 4q x 2k microtile. Log2 grouped as products of 4 (4 O(1)-range
// factors cannot over/underflow fp32) -> 4x fewer v_log_f32. Inline row sums.
// ---------------------------------------------------------------------------
__global__ __launch_bounds__(256) void dist_kernel(const float* __restrict__ aq,
                                                   const float* __restrict__ ak,
                                                   const float* __restrict__ mq,
                                                   const float* __restrict__ mk,
                                                   float* __restrict__ dist) {
  const int blk = blockIdx.x;
  const int h = blk / 72;
  const int tt = blk % 72;
  int qt = (int)sqrtf((float)tt);
  while ((qt + 1) * (qt + 2) <= tt) ++qt;
  while (qt * (qt + 1) > tt) --qt;
  const int kt = tt - qt * (qt + 1);   // 0 .. 2*qt+1

  __shared__ float aqs[64][68], mqs[64][68], aks[32][68], mks[32][68];
  __shared__ float lsum[96][2];
  const int t = threadIdx.x;
#pragma unroll
  for (int i = 0; i < 4; ++i) {
    int idx = t + 256 * i;          // 0..1023: q rows
    int r = idx >> 4, c4 = idx & 15;
    int gq = (qt * 64 + r) * DM + h * 64 + c4 * 4;
    *(float4*)&aqs[r][c4 * 4] = *(const float4*)&aq[gq];
    *(float4*)&mqs[r][c4 * 4] = *(const float4*)&mq[gq];
  }
#pragma unroll
  for (int i = 0; i < 2; ++i) {
    int idx = t + 256 * i;          // 0..511: k rows
    int r = idx >> 4, c4 = idx & 15;
    int gk = (kt * 32 + r) * DM + h * 64 + c4 * 4;
    *(float4*)&aks[r][c4 * 4] = *(const float4*)&ak[gk];
    *(float4*)&mks[r][c4 * 4] = *(const float4*)&mk[gk];
  }
  __syncthreads();

  if (t < 192) {
    int row = t >> 1, par = t & 1;
    const float* src = (row < 64) ? &aqs[row][0] : &aks[row - 64][0];
    float s = 0.f;
#pragma unroll
    for (int d = 0; d < 32; d += 4) {
      float pr = src[par * 32 + d] * src[par * 32 + d + 1]
               * src[par * 32 + d + 2] * src[par * 32 + d + 3];
      s += __log2f(pr);
    }
    lsum[row][par] = s;
  }
  __syncthreads();

  const int tq = t >> 4, tk = t & 15;
  float accl[4][2], acct[4][2];
#pragma unroll
  for (int i = 0; i < 4; ++i)
#pragma unroll
    for (int j = 0; j < 2; ++j) { accl[i][j] = 0.f; acct[i][j] = 0.f; }

#pragma unroll 2
  for (int d4 = 0; d4 < 16; ++d4) {
    float4 qa[4], qm[4], ka[2], km[2];
#pragma unroll
    for (int i = 0; i < 4; ++i) {
      qa[i] = *(const float4*)&aqs[tq * 4 + i][d4 * 4];
      qm[i] = *(const float4*)&mqs[tq * 4 + i][d4 * 4];
    }
#pragma unroll
    for (int j = 0; j < 2; ++j) {
      ka[j] = *(const float4*)&aks[tk + 16 * j][d4 * 4];
      km[j] = *(const float4*)&mks[tk + 16 * j][d4 * 4];
    }
#pragma unroll
    for (int i = 0; i < 4; ++i) {
      float qav[4] = {qa[i].x, qa[i].y, qa[i].z, qa[i].w};
      float qmv[4] = {qm[i].x, qm[i].y, qm[i].z, qm[i].w};
#pragma unroll
      for (int j = 0; j < 2; ++j) {
        float kav[4] = {ka[j].x, ka[j].y, ka[j].z, ka[j].w};
        float kmv[4] = {km[j].x, km[j].y, km[j].z, km[j].w};
        float pr = 1.f;
#pragma unroll
        for (int e = 0; e < 4; ++e) {
          float s = qav[e] + kav[e];
          pr = (e == 0) ? s : pr * s;
          float dm = qmv[e] - kmv[e];
          float rcp = __builtin_amdgcn_rcpf(s - EPSV);
          acct[i][j] = fmaf(dm * dm, rcp, acct[i][j]);
        }
        accl[i][j] += __log2f(pr);
      }
    }
  }

  const int qg0 = qt * 64 + tq * 4;
#pragma unroll
  for (int i = 0; i < 4; ++i) {
    float la2 = lsum[tq * 4 + i][0] + lsum[tq * 4 + i][1];
#pragma unroll
    for (int j = 0; j < 2; ++j) {
      int kg = kt * 32 + tk + 16 * j;
      float lc2 = lsum[64 + tk + 16 * j][0] + lsum[64 + tk + 16 * j][1];
      float dv = (LN2F * (0.5f * accl[i][j] - 0.25f * (la2 + lc2) - 32.f)
                  + 0.25f * acct[i][j]) * 0.125f;
      dist[((size_t)(h * SEQ) + qg0 + i) * SEQ + kg] = dv;
    }
  }
}

// ---------------------------------------------------------------------------
// Kernel S: causal softmax. Lane owns k-octet; fully-masked lanes skip the
// dist load. Store-skip: pv only reads octets with l*8 <= (q|31) (its panel
// k-extent), so octets beyond that skip the store too (~45% fewer stores);
// the masked-but-read zeros (q < l*8 <= q|31) are still written.
// aPack is bf16 HI-ONLY.
// ---------------------------------------------------------------------------
__global__ __launch_bounds__(256) void softmax_kernel(const float* __restrict__ dist,
                                                      unsigned short* __restrict__ aPack) {
  const int t = threadIdx.x;
  const int wid = blockIdx.x * 4 + (t >> 6);   // h*512+q
  const int l = t & 63;
  const int h = wid >> 9;
  const int q = wid & 511;
  const float* row = dist + (size_t)wid * SEQ;

  float vals[8];
  float m = -1e30f;
  if (l * 8 <= q) {            // causal skip: masked octets load nothing
    float4 v0 = *(const float4*)&row[l * 8];
    float4 v1 = *(const float4*)&row[l * 8 + 4];
    vals[0] = v0.x; vals[1] = v0.y; vals[2] = v0.z; vals[3] = v0.w;
    vals[4] = v1.x; vals[5] = v1.y; vals[6] = v1.z; vals[7] = v1.w;
#pragma unroll
    for (int e = 0; e < 8; ++e) {
      vals[e] = (l * 8 + e <= q) ? vals[e] : -1e30f;
      m = fmaxf(m, vals[e]);
    }
  } else {
#pragma unroll
    for (int e = 0; e < 8; ++e) vals[e] = -1e30f;
  }
#pragma unroll
  for (int o = 32; o; o >>= 1) m = fmaxf(m, __shfl_xor(m, o, 64));
  float ssum = 0.f;
#pragma unroll
  for (int e = 0; e < 8; ++e) {
    float p = (l * 8 + e <= q) ? __expf(vals[e] - m) : 0.f;
    vals[e] = p;
    ssum += p;
  }
#pragma unroll
  for (int o = 32; o; o >>= 1) ssum += __shfl_xor(ssum, o, 64);
  float rs = 1.f / ssum;

  if (l * 8 <= (q | 31)) {     // store-skip: beyond panel extent, pv never reads
    ushort8v hi;
#pragma unroll
    for (int e = 0; e < 8; ++e) hi[e] = f2bf(vals[e] * rs);
    unsigned short* dst = aPack + (size_t)h * 262144 + (q >> 5) * 16384 + l * 256 + (q & 31) * 8;
    *(ushort8v*)dst = hi;
  }
}

// ---------------------------------------------------------------------------
// Kernel V: PV via MFMA, P hi-only: 2 MFMAs per K=16 step (a1b1 + a1b2).
// Grid 512 x 64 threads (one wave per block; b = h*64 + qt*4 + mm*2 + dt):
// 2 blocks/CU average, adjacent blocks share (h,qt) aPack panels in cache,
// and the causally-imbalanced nks (2..34 steps) packs better. Causal k only.
// ---------------------------------------------------------------------------
__global__ __launch_bounds__(64) void pv_mfma_kernel(const unsigned short* __restrict__ aPack,
                                                     const unsigned short* __restrict__ vPack,
                                                     float* __restrict__ out) {
  const int b = blockIdx.x;         // h*64 + qt*4 + mm*2 + dt
  const int h = b >> 6;
  const int qt = (b >> 2) & 15;
  const int mm = (b >> 1) & 1;
  const int dt = b & 1;
  const int l = threadIdx.x & 63;

  const unsigned short* aBase = aPack + (size_t)h * 262144 + qt * 16384
                                + (l >> 5) * 256 + (l & 31) * 8;
  const unsigned short* vBase = vPack + (size_t)(h * 2 + mm) * 65536 + dt * 16384
                                + (l >> 5) * 256 + (l & 31) * 8;

  f32x16 acc = {};
  const int nks = 2 * qt + 2;   // K=16 steps covering k <= qt*32+31
#pragma unroll 2
  for (int s = 0; s < nks; ++s) {
    short8v a1 = *(const short8v*)(aBase + (size_t)s * 512);
    short8v b1 = *(const short8v*)(vBase + (size_t)s * 512);
    short8v b2 = *(const short8v*)(vBase + 32768 + (size_t)s * 512);
    acc = __builtin_amdgcn_mfma_f32_32x32x16_bf16(a1, b1, acc, 0, 0, 0);
    acc = __builtin_amdgcn_mfma_f32_32x32x16_bf16(a1, b2, acc, 0, 0, 0);
  }

  float* dst = out + ((mm == 0) ? 0 : (size_t)NH * SEQ * DKH);
  const int col = dt * 32 + (l & 31);
#pragma unroll
  for (int i = 0; i < 16; ++i) {
    int qrow = (i & 3) + 8 * (i >> 2) + 4 * (l >> 5);
    int q = qt * 32 + qrow;
    float v = acc[i];
    if (mm) v = sqrtf(fmaxf(v, 0.f) + EPSV);
    dst[((size_t)h * SEQ + q) * DKH + col] = v;
  }
}

// ---------------------------------------------------------------------------
extern "C" void kernel_launch(void* const* d_in, const int* in_sizes, int n_in,
                              void* d_out, int out_size, void* d_ws, size_t ws_size,
                              hipStream_t stream) {
  (void)in_sizes; (void)n_in; (void)out_size; (void)ws_size;

  float* ws = (float*)d_ws;
  float* mq = ws;                 // 512*512 each
  float* mk = mq + 262144;
  float* mv = mk + 262144;        // unused (p=2 emits vPack directly)
  float* sq = mv + 262144;        // aq = sigma_q^2 + eps (proj epilogue)
  float* sk = sq + 262144;        // ak = sigma_k^2 + eps
  float* sv = sk + 262144;        // unused (p=5 emits vPack directly)
  // pack region: 18 MB, dead after the proj GEMM; dist (8 MB) + aPack (4 MB)
  // alias it. vPack lives OUTSIDE pack (proj writes it while reading pack).
  unsigned short* pack = (unsigned short*)(sv + 262144);
  float* dist = (float*)pack;                         // [0, 8MB)
  unsigned short* aPack = pack + 4194304;             // [8MB, 12MB)
  unsigned short* vPack = pack + 9437184;             // [18MB, 20MB)

  ConvArgs ca;
  ca.src[0] = (const float*)d_in[0];
  ca.src[1] = (const float*)d_in[1];
  ca.src[2] = (const float*)d_in[2];
  ca.src[3] = (const float*)d_in[3];
  ca.src[4] = (const float*)d_in[4];
  ca.src[5] = (const float*)d_in[5];
  ca.src[6] = (const float*)d_in[6];
  ca.src[7] = (const float*)d_in[8];
  ca.src[8] = (const float*)d_in[10];
  ca.src[9] = (const float*)d_in[12];
  ca.src[10] = (const float*)d_in[14];
  ca.src[11] = (const float*)d_in[16];

  GemmArgs gaArgs;
  gaArgs.bias[0] = (const float*)d_in[7];  gaArgs.out[0] = mq;
  gaArgs.bias[1] = (const float*)d_in[9];  gaArgs.out[1] = mk;
  gaArgs.bias[2] = (const float*)d_in[11]; gaArgs.out[2] = mv;
  gaArgs.bias[3] = (const float*)d_in[13]; gaArgs.out[3] = sq;
  gaArgs.bias[4] = (const float*)d_in[15]; gaArgs.out[4] = sk;
  gaArgs.bias[5] = (const float*)d_in[17]; gaArgs.out[5] = sv;
  gaArgs.vPack = vPack;

  convert_kernel<<<12 * 128, 256, 0, stream>>>(ca, pack);

  dim3 ggrid(8, 8, 6);
  mfma_proj_kernel<<<ggrid, 512, 0, stream>>>(pack, gaArgs);

  dist_kernel<<<8 * 72, 256, 0, stream>>>(sq, sk, mq, mk, dist);

  softmax_kernel<<<1024, 256, 0, stream>>>(dist, aPack);

  pv_mfma_kernel<<<512, 64, 0, stream>>>(aPack, vPack, (float*)d_out);
}